// Round 1
// baseline (3997.178 us; speedup 1.0000x reference)
//
#include <hip/hip_runtime.h>
#include <cstdint>
#include <cmath>

using u16 = unsigned short;

// ---------------- problem constants ----------------
constexpr int NR   = 32768;
constexpr int N0I  = 32,  N1I = 16;           // input:  32 scalars, 16 vectors
constexpr int N0H  = 128, N1H = 64, STP = 192; // hidden: 128 scalars, 64 vectors, 192 TP outputs
constexpr int P00_1 = 528, P11_1 = 136, P0_1 = 664;   // layer-1 scalar pair feats
constexpr int P1_1  = 512;                             // layer-1 vector pair feats (32*16)
constexpr int P00_2 = 8256, P11_2 = 2080, P0_2 = 10336;
constexpr int P1_2  = 8192;                            // 128*64

constexpr float INV_SQRT3 = 0.57735026918962576f;

// ---------------- workspace layout (bytes) ----------------
constexpr size_t O_MSS2 = 0;
constexpr size_t O_MDD2 = O_MSS2 + (size_t)P00_2 * 2;     // 16512
constexpr size_t O_MSS1 = O_MDD2 + (size_t)P11_2 * 2;     // 20672
constexpr size_t O_MDD1 = O_MSS1 + (size_t)P00_1 * 2;     // 21728
constexpr size_t O_W0T1 = 22016;                          // 256-aligned
constexpr size_t O_W0T2 = O_W0T1 + (size_t)P0_1 * STP * 4;
constexpr size_t O_S1   = O_W0T2 + (size_t)P0_2 * STP * 4;
constexpr size_t O_V1   = O_S1 + (size_t)NR * N0H * 4;
constexpr size_t O_S2   = O_V1 + (size_t)NR * (N1H * 3) * 4;
constexpr size_t O_G2   = O_S2 + (size_t)NR * N0H * 4;
constexpr size_t O_V2   = O_G2 + (size_t)NR * N1H * 4;
constexpr size_t WS_NEED = O_V2 + (size_t)NR * (N1H * 3) * 4;  // ~96 MB

// ---------------- map init (runs every call; ws is poisoned before timing) ----------------
__global__ void k_init_maps(u16* mss2, u16* mdd2, u16* mss1, u16* mdd1) {
  const int t = threadIdx.x;
  if (t < N0H) { int u = t, base = u*N0H - u*(u-1)/2;
    for (int v = u; v < N0H; ++v) mss2[base + v - u] = (u16)((u<<8)|v); }
  if (t < N1H) { int u = t, base = u*N1H - u*(u-1)/2;
    for (int v = u; v < N1H; ++v) mdd2[base + v - u] = (u16)((u<<8)|v); }
  if (t < N0I) { int u = t, base = u*N0I - u*(u-1)/2;
    for (int v = u; v < N0I; ++v) mss1[base + v - u] = (u16)((u<<8)|v); }
  if (t < N1I) { int u = t, base = u*N1I - u*(u-1)/2;
    for (int v = u; v < N1I; ++v) mdd1[base + v - u] = (u16)((u<<8)|v); }
}

// ---------------- tiled transpose: in[R][C] -> out[C][R] ----------------
__global__ void k_transpose(const float* __restrict__ in, float* __restrict__ out, int R, int C) {
  __shared__ float tile[32][33];
  const int c0 = blockIdx.x * 32, rr0 = blockIdx.y * 32;
  const int tx = threadIdx.x, ty = threadIdx.y;
  #pragma unroll
  for (int k = 0; k < 32; k += 8) {
    int r = rr0 + ty + k, c = c0 + tx;
    if (r < R && c < C) tile[ty + k][tx] = in[(size_t)r * C + c];
  }
  __syncthreads();
  #pragma unroll
  for (int k = 0; k < 32; k += 8) {
    int c = c0 + ty + k, r = rr0 + tx;
    if (c < C && r < R) out[(size_t)c * R + r] = tile[tx][ty + k];
  }
}

// ---------------- layer 1 (tensor square + gate), 32 rows/block ----------------
__global__ __launch_bounds__(256) void k_layer1(
    const float* __restrict__ x,
    const float* __restrict__ w0t,   // [P0_1][192]
    const float* __restrict__ w1,    // [64][512]
    const u16* __restrict__ mss, const u16* __restrict__ mdd,
    float* __restrict__ s1, float* __restrict__ v1)
{
  __shared__ float sS[32*33];
  __shared__ float sV[32*49];
  __shared__ u16   sMs[P00_1];
  __shared__ u16   sMd[P11_1];
  __shared__ float sPS[32*665];
  __shared__ float sB[32*196];   // B chunk, later reused to hold normalized out_s

  const int tid = threadIdx.x;
  const int r0  = blockIdx.x * 32;

  for (int i = tid; i < P00_1; i += 256) sMs[i] = mss[i];
  for (int i = tid; i < P11_1; i += 256) sMd[i] = mdd[i];
  for (int i = tid; i < 32*80; i += 256) {
    int r = i / 80, c = i - r*80;
    float val = x[(size_t)(r0 + r)*80 + c];
    if (c < N0I) sS[r*33 + c] = val;
    else         sV[r*49 + (c - N0I)] = val;
  }
  __syncthreads();

  // pair features in LDS
  for (int i = tid; i < 32*P0_1; i += 256) {
    int r = i / P0_1, p = i - r*P0_1;
    float a;
    if (p < P00_1) {
      u16 mv = sMs[p]; int u = mv >> 8, v = mv & 255;
      a = sS[r*33 + u] * sS[r*33 + v];
    } else {
      u16 mv = sMd[p - P00_1]; int u = mv >> 8, v = mv & 255;
      const float* pa = &sV[r*49 + u*3];
      const float* pb = &sV[r*49 + v*3];
      a = (pa[0]*pb[0] + pa[1]*pb[1] + pa[2]*pb[2]) * INV_SQRT3;
    }
    sPS[r*665 + p] = a;
  }

  const int tr = tid & 15, tm = tid >> 4;   // rows tr*2..+1, m = tm*12..+11
  float acc[2][12];
  #pragma unroll
  for (int i = 0; i < 2; ++i)
    #pragma unroll
    for (int j = 0; j < 12; ++j) acc[i][j] = 0.f;

  for (int p0 = 0; p0 < P0_1; p0 += 32) {
    const int kc = min(32, P0_1 - p0);
    __syncthreads();
    for (int i4 = tid; i4 < kc*48; i4 += 256) {
      int e = i4*4, pp = e/192, m = e - pp*192;
      float4 b = *(const float4*)&w0t[(size_t)(p0 + pp)*STP + m];
      float* d = &sB[pp*196 + m];
      d[0]=b.x; d[1]=b.y; d[2]=b.z; d[3]=b.w;
    }
    __syncthreads();
    for (int pp = 0; pp < kc; ++pp) {
      float a0 = sPS[(tr*2    )*665 + p0 + pp];
      float a1 = sPS[(tr*2 + 1)*665 + p0 + pp];
      const float* bp = &sB[pp*196 + tm*12];
      #pragma unroll
      for (int j = 0; j < 12; ++j) {
        float b = bp[j];
        acc[0][j] = fmaf(a0, b, acc[0][j]);
        acc[1][j] = fmaf(a1, b, acc[1][j]);
      }
    }
  }
  __syncthreads();
  {
    const float nrm = 1.0f / sqrtf((float)P0_1);
    #pragma unroll
    for (int i = 0; i < 2; ++i) {
      int r = tr*2 + i;
      #pragma unroll
      for (int j = 0; j < 12; ++j) sB[r*196 + tm*12 + j] = acc[i][j] * nrm;
    }
  }
  __syncthreads();

  // scalar outputs: silu
  for (int i = tid; i < 32*N0H; i += 256) {
    int r = i >> 7, u = i & 127;
    float val = sB[r*196 + u];
    s1[(size_t)(r0 + r)*N0H + u] = val / (1.f + __expf(-val));
  }
  // vector outputs: factorized einsum + sigmoid gate
  const float nv = 1.0f / sqrtf((float)P1_1);
  for (int i = tid; i < 32*N1H; i += 256) {
    int r = i >> 6, m = i & 63;
    float T[16];
    #pragma unroll
    for (int w = 0; w < 16; ++w) T[w] = 0.f;
    const float* wrow = &w1[(size_t)m * P1_1];
    for (int u = 0; u < N0I; ++u) {
      float sv = sS[r*33 + u];
      #pragma unroll
      for (int w = 0; w < 16; w += 4) {
        float4 w4 = *(const float4*)&wrow[u*16 + w];
        T[w]   = fmaf(sv, w4.x, T[w]);   T[w+1] = fmaf(sv, w4.y, T[w+1]);
        T[w+2] = fmaf(sv, w4.z, T[w+2]); T[w+3] = fmaf(sv, w4.w, T[w+3]);
      }
    }
    float gv = sB[r*196 + N0H + m];
    gv = 1.f / (1.f + __expf(-gv));
    float o0=0.f, o1=0.f, o2=0.f;
    #pragma unroll
    for (int w = 0; w < 16; ++w) {
      float t = T[w];
      const float* vp = &sV[r*49 + w*3];
      o0 = fmaf(t, vp[0], o0); o1 = fmaf(t, vp[1], o1); o2 = fmaf(t, vp[2], o2);
    }
    const float sc = gv * nv;
    float* vo = &v1[(size_t)(r0 + r)*(N1H*3) + m*3];
    vo[0] = o0*sc; vo[1] = o1*sc; vo[2] = o2*sc;
  }
}

// ---------------- layer 2 scalar path: on-the-fly feature GEMM, 64 rows/block ----------------
__global__ __launch_bounds__(256) void k_l2_scalar(
    const float* __restrict__ s1, const float* __restrict__ v1,
    const float* __restrict__ w0t,  // [P0_2][192]
    const u16* __restrict__ mss, const u16* __restrict__ mdd,
    float* __restrict__ s2, float* __restrict__ g2)
{
  __shared__ float sSV[64*193];    // union: s as [64][129], then v as [64][193]
  __shared__ float sA[32*64];
  __shared__ float sB[32*196];
  __shared__ u16 sMs[P00_2];
  __shared__ u16 sMd[P11_2];

  const int tid = threadIdx.x;
  const int r0 = blockIdx.x * 64;
  const int tr = tid & 15, tm = tid >> 4;   // rows tr*4..+3, m = tm*12..+11

  for (int i = tid; i < P00_2; i += 256) sMs[i] = mss[i];
  for (int i = tid; i < P11_2; i += 256) sMd[i] = mdd[i];
  for (int i = tid; i < 64*N0H; i += 256) {
    int r = i >> 7, c = i & 127;
    sSV[r*129 + c] = s1[(size_t)(r0 + r)*N0H + c];
  }

  float acc[4][12];
  #pragma unroll
  for (int i = 0; i < 4; ++i)
    #pragma unroll
    for (int j = 0; j < 12; ++j) acc[i][j] = 0.f;

  // ---- ss features (8256 = 258*32) ----
  for (int c = 0; c < P00_2/32; ++c) {
    const int p0 = c*32;
    __syncthreads();
    #pragma unroll
    for (int k = 0; k < 8; ++k) {
      int idx = tid + k*256, pp = idx >> 6, r = idx & 63;
      u16 mv = sMs[p0 + pp]; int u = mv >> 8, v = mv & 255;
      sA[pp*64 + r] = sSV[r*129 + u] * sSV[r*129 + v];
    }
    #pragma unroll
    for (int k = 0; k < 6; ++k) {
      int i4 = tid + k*256, e = i4*4, pp = e/192, m = e - pp*192;
      float4 b = *(const float4*)&w0t[(size_t)(p0 + pp)*STP + m];
      float* d = &sB[pp*196 + m];
      d[0]=b.x; d[1]=b.y; d[2]=b.z; d[3]=b.w;
    }
    __syncthreads();
    #pragma unroll 2
    for (int pp = 0; pp < 32; ++pp) {
      float4 a = *(const float4*)&sA[pp*64 + tr*4];
      const float* bp = &sB[pp*196 + tm*12];
      float4 b0 = *(const float4*)(bp);
      float4 b1 = *(const float4*)(bp + 4);
      float4 b2 = *(const float4*)(bp + 8);
      const float ar[4]  = {a.x, a.y, a.z, a.w};
      const float br[12] = {b0.x,b0.y,b0.z,b0.w,b1.x,b1.y,b1.z,b1.w,b2.x,b2.y,b2.z,b2.w};
      #pragma unroll
      for (int i = 0; i < 4; ++i)
        #pragma unroll
        for (int j = 0; j < 12; ++j) acc[i][j] = fmaf(ar[i], br[j], acc[i][j]);
    }
  }

  // ---- swap tile: v in place of s ----
  __syncthreads();
  for (int i = tid; i < 64*192; i += 256) {
    int r = i / 192, c = i - r*192;
    sSV[r*193 + c] = v1[(size_t)(r0 + r)*192 + c];
  }

  // ---- dd features (2080 = 65*32) ----
  for (int c = 0; c < P11_2/32; ++c) {
    const int q0 = c*32;
    __syncthreads();
    #pragma unroll
    for (int k = 0; k < 8; ++k) {
      int idx = tid + k*256, pp = idx >> 6, r = idx & 63;
      u16 mv = sMd[q0 + pp]; int u = mv >> 8, v = mv & 255;
      const float* pa = &sSV[r*193 + u*3];
      const float* pb = &sSV[r*193 + v*3];
      sA[pp*64 + r] = (pa[0]*pb[0] + pa[1]*pb[1] + pa[2]*pb[2]) * INV_SQRT3;
    }
    #pragma unroll
    for (int k = 0; k < 6; ++k) {
      int i4 = tid + k*256, e = i4*4, pp = e/192, m = e - pp*192;
      float4 b = *(const float4*)&w0t[(size_t)(P00_2 + q0 + pp)*STP + m];
      float* d = &sB[pp*196 + m];
      d[0]=b.x; d[1]=b.y; d[2]=b.z; d[3]=b.w;
    }
    __syncthreads();
    #pragma unroll 2
    for (int pp = 0; pp < 32; ++pp) {
      float4 a = *(const float4*)&sA[pp*64 + tr*4];
      const float* bp = &sB[pp*196 + tm*12];
      float4 b0 = *(const float4*)(bp);
      float4 b1 = *(const float4*)(bp + 4);
      float4 b2 = *(const float4*)(bp + 8);
      const float ar[4]  = {a.x, a.y, a.z, a.w};
      const float br[12] = {b0.x,b0.y,b0.z,b0.w,b1.x,b1.y,b1.z,b1.w,b2.x,b2.y,b2.z,b2.w};
      #pragma unroll
      for (int i = 0; i < 4; ++i)
        #pragma unroll
        for (int j = 0; j < 12; ++j) acc[i][j] = fmaf(ar[i], br[j], acc[i][j]);
    }
  }

  // epilogue: normalize, silu for scalars / sigmoid for gates
  const float nrm = 1.0f / sqrtf((float)P0_2);
  #pragma unroll
  for (int i = 0; i < 4; ++i) {
    const int gr = r0 + tr*4 + i;
    #pragma unroll
    for (int j = 0; j < 12; ++j) {
      const int m = tm*12 + j;
      float val = acc[i][j] * nrm;
      float sg = 1.f / (1.f + __expf(-val));
      if (m < N0H) s2[(size_t)gr*N0H + m] = val * sg;
      else         g2[(size_t)gr*N1H + (m - N0H)] = sg;
    }
  }
}

// ---------------- layer 2 vector path: factorized einsum, 64 rows/block ----------------
__global__ __launch_bounds__(256) void k_l2_vector(
    const float* __restrict__ s1, const float* __restrict__ v1,
    const float* __restrict__ w1,   // [64][8192], p = u*64 + w
    const float* __restrict__ g2,
    float* __restrict__ v2)
{
  __shared__ float sS[64*129];
  __shared__ float sV[64*193];
  __shared__ float sW[2*8192];   // double-buffered W1_2[m] rows

  const int tid = threadIdx.x;
  const int r0 = blockIdx.x * 64;
  const int r = tid >> 2, wq = tid & 3;   // 64 rows x 4 w-quarters

  for (int i = tid; i < 64*128; i += 256) {
    int rr = i >> 7, c = i & 127;
    sS[rr*129 + c] = s1[(size_t)(r0 + rr)*128 + c];
  }
  for (int i = tid; i < 64*192; i += 256) {
    int rr = i / 192, c = i - rr*192;
    sV[rr*193 + c] = v1[(size_t)(r0 + rr)*192 + c];
  }
  #pragma unroll
  for (int k = 0; k < 8; ++k) {
    float4 t = *(const float4*)&w1[tid*4 + k*1024];
    *(float4*)&sW[tid*4 + k*1024] = t;
  }
  __syncthreads();

  const float* srow = &sS[r*129];
  const float* vrow = &sV[r*193 + wq*48];
  const float nrm = 1.0f / sqrtf((float)P1_2);

  for (int m = 0; m < 64; ++m) {
    const int cur = m & 1;
    float4 pre[8];
    if (m + 1 < 64) {
      #pragma unroll
      for (int k = 0; k < 8; ++k)
        pre[k] = *(const float4*)&w1[(size_t)(m+1)*8192 + tid*4 + k*1024];
    }
    float T[16];
    #pragma unroll
    for (int k = 0; k < 16; ++k) T[k] = 0.f;
    const float* wb = &sW[cur*8192 + wq*16];
    #pragma unroll 4
    for (int u = 0; u < 128; ++u) {
      float sv = srow[u];
      #pragma unroll
      for (int k = 0; k < 16; k += 4) {
        float4 w4 = *(const float4*)&wb[u*64 + k];
        T[k]   = fmaf(sv, w4.x, T[k]);   T[k+1] = fmaf(sv, w4.y, T[k+1]);
        T[k+2] = fmaf(sv, w4.z, T[k+2]); T[k+3] = fmaf(sv, w4.w, T[k+3]);
      }
    }
    float o0=0.f, o1=0.f, o2=0.f;
    #pragma unroll
    for (int k = 0; k < 16; ++k) {
      float t = T[k];
      o0 = fmaf(t, vrow[k*3+0], o0);
      o1 = fmaf(t, vrow[k*3+1], o1);
      o2 = fmaf(t, vrow[k*3+2], o2);
    }
    o0 += __shfl_down(o0, 2, 4); o0 += __shfl_down(o0, 1, 4);
    o1 += __shfl_down(o1, 2, 4); o1 += __shfl_down(o1, 1, 4);
    o2 += __shfl_down(o2, 2, 4); o2 += __shfl_down(o2, 1, 4);
    if (wq == 0) {
      float g = g2[(size_t)(r0 + r)*64 + m] * nrm;
      float* vo = &v2[(size_t)(r0 + r)*192 + m*3];
      vo[0] = o0*g; vo[1] = o1*g; vo[2] = o2*g;
    }
    if (m + 1 < 64) {
      #pragma unroll
      for (int k = 0; k < 8; ++k)
        *(float4*)&sW[(cur^1)*8192 + tid*4 + k*1024] = pre[k];
    }
    __syncthreads();
  }
}

// ---------------- final: pair feats . W0_f, 8 rows/block ----------------
__global__ __launch_bounds__(256) void k_final(
    const float* __restrict__ s2, const float* __restrict__ v2,
    const float* __restrict__ wf,
    const u16* __restrict__ mss, const u16* __restrict__ mdd,
    float* __restrict__ out)
{
  __shared__ float sS[8*129];
  __shared__ float sV[8*193];
  __shared__ u16 sMs[P00_2];
  __shared__ u16 sMd[P11_2];

  const int tid = threadIdx.x;
  const int r0 = blockIdx.x * 8;
  for (int i = tid; i < P00_2; i += 256) sMs[i] = mss[i];
  for (int i = tid; i < P11_2; i += 256) sMd[i] = mdd[i];
  for (int i = tid; i < 8*128; i += 256) { int r = i >> 7, c = i & 127; sS[r*129+c] = s2[(size_t)(r0+r)*128 + c]; }
  for (int i = tid; i < 8*192; i += 256) { int r = i / 192, c = i - r*192; sV[r*193+c] = v2[(size_t)(r0+r)*192 + c]; }
  __syncthreads();

  const int r = tid >> 5, l = tid & 31;
  const float* srow = &sS[r*129];
  const float* vrow = &sV[r*193];
  float acc = 0.f;
  for (int p = l; p < P00_2; p += 32) {
    u16 mv = sMs[p]; int u = mv >> 8, v = mv & 255;
    acc = fmaf(wf[p], srow[u]*srow[v], acc);
  }
  for (int q = l; q < P11_2; q += 32) {
    u16 mv = sMd[q]; int u = mv >> 8, v = mv & 255;
    const float* pa = &vrow[u*3];
    const float* pb = &vrow[v*3];
    float d = (pa[0]*pb[0] + pa[1]*pb[1] + pa[2]*pb[2]) * INV_SQRT3;
    acc = fmaf(wf[P00_2 + q], d, acc);
  }
  #pragma unroll
  for (int off = 16; off >= 1; off >>= 1) acc += __shfl_down(acc, off, 32);
  if (l == 0) out[r0 + r] = acc * (1.0f / sqrtf((float)P0_2));
}

// ---------------- launch ----------------
extern "C" void kernel_launch(void* const* d_in, const int* in_sizes, int n_in,
                              void* d_out, int out_size, void* d_ws, size_t ws_size,
                              hipStream_t stream)
{
  const float* x    = (const float*)d_in[0];
  const float* w0_1 = (const float*)d_in[1];
  const float* w1_1 = (const float*)d_in[2];
  const float* w0_2 = (const float*)d_in[3];
  const float* w1_2 = (const float*)d_in[4];
  const float* w0_f = (const float*)d_in[5];
  float* out = (float*)d_out;
  char* ws = (char*)d_ws;

  if (ws_size < WS_NEED) return;  // fail loudly via validation rather than corrupt memory

  u16* mss2 = (u16*)(ws + O_MSS2);
  u16* mdd2 = (u16*)(ws + O_MDD2);
  u16* mss1 = (u16*)(ws + O_MSS1);
  u16* mdd1 = (u16*)(ws + O_MDD1);
  float* w0t1 = (float*)(ws + O_W0T1);
  float* w0t2 = (float*)(ws + O_W0T2);
  float* s1 = (float*)(ws + O_S1);
  float* v1 = (float*)(ws + O_V1);
  float* s2 = (float*)(ws + O_S2);
  float* g2 = (float*)(ws + O_G2);
  float* v2 = (float*)(ws + O_V2);

  hipLaunchKernelGGL(k_init_maps, dim3(1), dim3(128), 0, stream, mss2, mdd2, mss1, mdd1);
  hipLaunchKernelGGL(k_transpose, dim3((P0_1 + 31)/32, STP/32), dim3(32, 8), 0, stream,
                     w0_1, w0t1, STP, P0_1);
  hipLaunchKernelGGL(k_transpose, dim3(P0_2/32, STP/32), dim3(32, 8), 0, stream,
                     w0_2, w0t2, STP, P0_2);
  hipLaunchKernelGGL(k_layer1, dim3(NR/32), dim3(256), 0, stream,
                     x, w0t1, w1_1, mss1, mdd1, s1, v1);
  hipLaunchKernelGGL(k_l2_scalar, dim3(NR/64), dim3(256), 0, stream,
                     s1, v1, w0t2, mss2, mdd2, s2, g2);
  hipLaunchKernelGGL(k_l2_vector, dim3(NR/64), dim3(256), 0, stream,
                     s1, v1, w1_2, g2, v2);
  hipLaunchKernelGGL(k_final, dim3(NR/8), dim3(256), 0, stream,
                     s2, v2, w0_f, mss2, mdd2, out);
}

// Round 2
// 2145.177 us; speedup vs baseline: 1.8633x; 1.8633x over previous
//
#include <hip/hip_runtime.h>
#include <cstdint>
#include <cmath>

using u16 = unsigned short;
typedef __attribute__((ext_vector_type(8))) short  short8;
typedef __attribute__((ext_vector_type(4))) float  f32x4;

// ---------------- problem constants ----------------
constexpr int NR   = 32768;
constexpr int N0I  = 32,  N1I = 16;
constexpr int N0H  = 128, N1H = 64, STP = 192;
constexpr int P00_1 = 528, P11_1 = 136, P0_1 = 664;
constexpr int P1_1  = 512;
constexpr int P00_2 = 8256, P11_2 = 2080, P0_2 = 10336;
constexpr int P1_2  = 8192;
constexpr int NCH_SS = P00_2 / 32;   // 258
constexpr int NCH    = P0_2 / 32;    // 323

constexpr float INV_SQRT3 = 0.57735026918962576f;

// ---------------- workspace layout (bytes) ----------------
constexpr size_t O_MSS2 = 0;
constexpr size_t O_MDD2 = O_MSS2 + (size_t)P00_2 * 2;
constexpr size_t O_MSS1 = O_MDD2 + (size_t)P11_2 * 2;
constexpr size_t O_MDD1 = O_MSS1 + (size_t)P00_1 * 2;
constexpr size_t O_W0T1 = 22016;
constexpr size_t O_W0F  = O_W0T1 + (size_t)P0_1 * STP * 4;            // frag-ordered hi/lo bf16 of W0_2
constexpr size_t O_S1   = O_W0F + (size_t)NCH * 12 * 1024 * 2;        // 323*12 groups * 1024 shorts * 2B
constexpr size_t O_V1   = O_S1 + (size_t)NR * N0H * 4;
constexpr size_t O_S2   = O_V1 + (size_t)NR * (N1H * 3) * 4;
constexpr size_t O_G2   = O_S2 + (size_t)NR * N0H * 4;
constexpr size_t O_V2   = O_G2 + (size_t)NR * N1H * 4;
constexpr size_t WS_NEED = O_V2 + (size_t)NR * (N1H * 3) * 4;

// ---------------- helpers ----------------
__device__ __forceinline__ unsigned short f2bf(float x) {
  unsigned u = __float_as_uint(x);
  u += 0x7fffu + ((u >> 16) & 1u);
  return (unsigned short)(u >> 16);
}
__device__ __forceinline__ float bf2f(unsigned short h) {
  return __uint_as_float(((unsigned)h) << 16);
}

// ---------------- map init ----------------
__global__ void k_init_maps(u16* mss2, u16* mdd2, u16* mss1, u16* mdd1) {
  const int t = threadIdx.x;
  if (t < N0H) { int u = t, base = u*N0H - u*(u-1)/2;
    for (int v = u; v < N0H; ++v) mss2[base + v - u] = (u16)((u<<8)|v); }
  if (t < N1H) { int u = t, base = u*N1H - u*(u-1)/2;
    for (int v = u; v < N1H; ++v) mdd2[base + v - u] = (u16)((u<<8)|v); }
  if (t < N0I) { int u = t, base = u*N0I - u*(u-1)/2;
    for (int v = u; v < N0I; ++v) mss1[base + v - u] = (u16)((u<<8)|v); }
  if (t < N1I) { int u = t, base = u*N1I - u*(u-1)/2;
    for (int v = u; v < N1I; ++v) mdd1[base + v - u] = (u16)((u<<8)|v); }
}

// ---------------- tiled transpose (for W0_1 only) ----------------
__global__ void k_transpose(const float* __restrict__ in, float* __restrict__ out, int R, int C) {
  __shared__ float tile[32][33];
  const int c0 = blockIdx.x * 32, rr0 = blockIdx.y * 32;
  const int tx = threadIdx.x, ty = threadIdx.y;
  #pragma unroll
  for (int k = 0; k < 32; k += 8) {
    int r = rr0 + ty + k, c = c0 + tx;
    if (r < R && c < C) tile[ty + k][tx] = in[(size_t)r * C + c];
  }
  __syncthreads();
  #pragma unroll
  for (int k = 0; k < 32; k += 8) {
    int c = c0 + ty + k, r = rr0 + tx;
    if (c < C && r < R) out[(size_t)c * R + r] = tile[tx][ty + k];
  }
}

// ---------------- prep: W0_2 -> MFMA B-fragment order, hi/lo bf16 ----------------
// group g = c*12 + nf; layout: w0f[g*1024 + plane*512 + lane*8 .. +7]
// B[k][n] = W0_2[n][k_global], k_global = c*32 + (lane>>4)*8 + j, n = nf*16 + (lane&15)
__global__ __launch_bounds__(256) void k_prep_b(const float* __restrict__ w0_2, short* __restrict__ w0f) {
  const int g = blockIdx.x * 4 + (threadIdx.x >> 6);
  const int lane = threadIdx.x & 63;
  if (g >= NCH * 12) return;
  const int c = g / 12, nf = g - c * 12;
  const int k = c * 32 + (lane >> 4) * 8;
  const int n = nf * 16 + (lane & 15);
  const float* src = &w0_2[(size_t)n * P0_2 + k];
  float4 f0 = *(const float4*)src;
  float4 f1 = *(const float4*)(src + 4);
  const float v[8] = {f0.x, f0.y, f0.z, f0.w, f1.x, f1.y, f1.z, f1.w};
  short8 h, l;
  #pragma unroll
  for (int j = 0; j < 8; ++j) {
    unsigned short hh = f2bf(v[j]);
    h[j] = (short)hh;
    l[j] = (short)f2bf(v[j] - bf2f(hh));
  }
  short* dst = w0f + (size_t)g * 1024 + lane * 8;
  *(short8*)dst = h;
  *(short8*)(dst + 512) = l;
}

// ---------------- layer 1 (unchanged this round) ----------------
__global__ __launch_bounds__(256) void k_layer1(
    const float* __restrict__ x,
    const float* __restrict__ w0t,
    const float* __restrict__ w1,
    const u16* __restrict__ mss, const u16* __restrict__ mdd,
    float* __restrict__ s1, float* __restrict__ v1)
{
  __shared__ float sS[32*33];
  __shared__ float sV[32*49];
  __shared__ u16   sMs[P00_1];
  __shared__ u16   sMd[P11_1];
  __shared__ float sPS[32*665];
  __shared__ float sB[32*196];

  const int tid = threadIdx.x;
  const int r0  = blockIdx.x * 32;

  for (int i = tid; i < P00_1; i += 256) sMs[i] = mss[i];
  for (int i = tid; i < P11_1; i += 256) sMd[i] = mdd[i];
  for (int i = tid; i < 32*80; i += 256) {
    int r = i / 80, c = i - r*80;
    float val = x[(size_t)(r0 + r)*80 + c];
    if (c < N0I) sS[r*33 + c] = val;
    else         sV[r*49 + (c - N0I)] = val;
  }
  __syncthreads();

  for (int i = tid; i < 32*P0_1; i += 256) {
    int r = i / P0_1, p = i - r*P0_1;
    float a;
    if (p < P00_1) {
      u16 mv = sMs[p]; int u = mv >> 8, v = mv & 255;
      a = sS[r*33 + u] * sS[r*33 + v];
    } else {
      u16 mv = sMd[p - P00_1]; int u = mv >> 8, v = mv & 255;
      const float* pa = &sV[r*49 + u*3];
      const float* pb = &sV[r*49 + v*3];
      a = (pa[0]*pb[0] + pa[1]*pb[1] + pa[2]*pb[2]) * INV_SQRT3;
    }
    sPS[r*665 + p] = a;
  }

  const int tr = tid & 15, tm = tid >> 4;
  float acc[2][12];
  #pragma unroll
  for (int i = 0; i < 2; ++i)
    #pragma unroll
    for (int j = 0; j < 12; ++j) acc[i][j] = 0.f;

  for (int p0 = 0; p0 < P0_1; p0 += 32) {
    const int kc = min(32, P0_1 - p0);
    __syncthreads();
    for (int i4 = tid; i4 < kc*48; i4 += 256) {
      int e = i4*4, pp = e/192, m = e - pp*192;
      float4 b = *(const float4*)&w0t[(size_t)(p0 + pp)*STP + m];
      float* d = &sB[pp*196 + m];
      d[0]=b.x; d[1]=b.y; d[2]=b.z; d[3]=b.w;
    }
    __syncthreads();
    for (int pp = 0; pp < kc; ++pp) {
      float a0 = sPS[(tr*2    )*665 + p0 + pp];
      float a1 = sPS[(tr*2 + 1)*665 + p0 + pp];
      const float* bp = &sB[pp*196 + tm*12];
      #pragma unroll
      for (int j = 0; j < 12; ++j) {
        float b = bp[j];
        acc[0][j] = fmaf(a0, b, acc[0][j]);
        acc[1][j] = fmaf(a1, b, acc[1][j]);
      }
    }
  }
  __syncthreads();
  {
    const float nrm = 1.0f / sqrtf((float)P0_1);
    #pragma unroll
    for (int i = 0; i < 2; ++i) {
      int r = tr*2 + i;
      #pragma unroll
      for (int j = 0; j < 12; ++j) sB[r*196 + tm*12 + j] = acc[i][j] * nrm;
    }
  }
  __syncthreads();

  for (int i = tid; i < 32*N0H; i += 256) {
    int r = i >> 7, u = i & 127;
    float val = sB[r*196 + u];
    s1[(size_t)(r0 + r)*N0H + u] = val / (1.f + __expf(-val));
  }
  const float nv = 1.0f / sqrtf((float)P1_1);
  for (int i = tid; i < 32*N1H; i += 256) {
    int r = i >> 6, m = i & 63;
    float T[16];
    #pragma unroll
    for (int w = 0; w < 16; ++w) T[w] = 0.f;
    const float* wrow = &w1[(size_t)m * P1_1];
    for (int u = 0; u < N0I; ++u) {
      float sv = sS[r*33 + u];
      #pragma unroll
      for (int w = 0; w < 16; w += 4) {
        float4 w4 = *(const float4*)&wrow[u*16 + w];
        T[w]   = fmaf(sv, w4.x, T[w]);   T[w+1] = fmaf(sv, w4.y, T[w+1]);
        T[w+2] = fmaf(sv, w4.z, T[w+2]); T[w+3] = fmaf(sv, w4.w, T[w+3]);
      }
    }
    float gv = sB[r*196 + N0H + m];
    gv = 1.f / (1.f + __expf(-gv));
    float o0=0.f, o1=0.f, o2=0.f;
    #pragma unroll
    for (int w = 0; w < 16; ++w) {
      float t = T[w];
      const float* vp = &sV[r*49 + w*3];
      o0 = fmaf(t, vp[0], o0); o1 = fmaf(t, vp[1], o1); o2 = fmaf(t, vp[2], o2);
    }
    const float sc = gv * nv;
    float* vo = &v1[(size_t)(r0 + r)*(N1H*3) + m*3];
    vo[0] = o0*sc; vo[1] = o1*sc; vo[2] = o2*sc;
  }
}

// ---------------- layer 2 scalar path: hi/lo-split bf16 MFMA GEMM ----------------
// Block: 64 rows, 256 threads = 4 waves in 2M x 2N grid.
// A (features) generated on the fly into double-buffered swizzled LDS bf16 hi/lo planes.
// B loaded directly global->VGPR from frag-ordered w0f (L2-hot).
__global__ __launch_bounds__(256) void k_l2_scalar_mfma(
    const float* __restrict__ s1, const float* __restrict__ v1,
    const short* __restrict__ w0f,
    const u16* __restrict__ mss, const u16* __restrict__ mdd,
    float* __restrict__ s2, float* __restrict__ g2)
{
  __shared__ float sSV[64*193];                 // s phase: [64][129]; v phase: [64][193]
  __shared__ __align__(16) short sA[2][2][2048]; // [buf][hi/lo][64 rows * 32 k] swizzled

  const int tid  = threadIdx.x;
  const int lane = tid & 63, wid = tid >> 6;
  const int wm = wid & 1, wn = wid >> 1;        // wave grid 2M x 2N
  const int r0 = blockIdx.x * 64;

  // feature-gen mapping: k-pair kp (k=2kp,2kp+1), rows rg*4..rg*4+3
  const int kp = tid & 15;
  const int rg = tid >> 4;

  // ---- stage s-tile [64][129] ----
  for (int i = tid; i < 64*128; i += 256) {
    int r = i >> 7, c = i & 127;
    sSV[r*129 + c] = s1[(size_t)(r0 + r)*N0H + c];
  }

  f32x4 acc[2][6];
  #pragma unroll
  for (int mi = 0; mi < 2; ++mi)
    #pragma unroll
    for (int q = 0; q < 6; ++q) acc[mi][q] = {0.f, 0.f, 0.f, 0.f};

  // swizzled A write: byte = m*64 + (((kp>>2) ^ ((m>>1)&3))<<4) + ((kp&3)<<2)
  auto write_feats_ss = [&](int buf, unsigned mv) {
    const int u0 = (mv >> 8) & 255,  v0 = mv & 255;
    const int u1 = (mv >> 24) & 255, v1i = (mv >> 16) & 255;
    char* a0 = (char*)&sA[buf][0][0];
    char* a1 = (char*)&sA[buf][1][0];
    #pragma unroll
    for (int i = 0; i < 4; ++i) {
      const int m = rg*4 + i;
      const float* sr = &sSV[m*129];
      float f0 = sr[u0] * sr[v0];
      float f1 = sr[u1] * sr[v1i];
      unsigned short h0 = f2bf(f0), h1 = f2bf(f1);
      unsigned short l0 = f2bf(f0 - bf2f(h0)), l1 = f2bf(f1 - bf2f(h1));
      const int off = m*64 + (((kp>>2) ^ ((m>>1)&3)) << 4) + ((kp&3) << 2);
      *(unsigned*)(a0 + off) = (unsigned)h0 | ((unsigned)h1 << 16);
      *(unsigned*)(a1 + off) = (unsigned)l0 | ((unsigned)l1 << 16);
    }
  };
  auto write_feats_dd = [&](int buf, unsigned mv) {
    const int u0 = (mv >> 8) & 255,  v0 = mv & 255;
    const int u1 = (mv >> 24) & 255, v1i = (mv >> 16) & 255;
    char* a0 = (char*)&sA[buf][0][0];
    char* a1 = (char*)&sA[buf][1][0];
    #pragma unroll
    for (int i = 0; i < 4; ++i) {
      const int m = rg*4 + i;
      const float* vr = &sSV[m*193];
      const float* pa0 = vr + u0*3; const float* pb0 = vr + v0*3;
      const float* pa1 = vr + u1*3; const float* pb1 = vr + v1i*3;
      float f0 = (pa0[0]*pb0[0] + pa0[1]*pb0[1] + pa0[2]*pb0[2]) * INV_SQRT3;
      float f1 = (pa1[0]*pb1[0] + pa1[1]*pb1[1] + pa1[2]*pb1[2]) * INV_SQRT3;
      unsigned short h0 = f2bf(f0), h1 = f2bf(f1);
      unsigned short l0 = f2bf(f0 - bf2f(h0)), l1 = f2bf(f1 - bf2f(h1));
      const int off = m*64 + (((kp>>2) ^ ((m>>1)&3)) << 4) + ((kp&3) << 2);
      *(unsigned*)(a0 + off) = (unsigned)h0 | ((unsigned)h1 << 16);
      *(unsigned*)(a1 + off) = (unsigned)l0 | ((unsigned)l1 << 16);
    }
  };

  auto mfma_step = [&](int c, int buf) {
    // B frags: this wave's 6 n-frags, hi+lo
    const short* bb = w0f + ((size_t)c * 12 + wn * 6) * 1024 + lane * 8;
    short8 bh[6], bl[6];
    #pragma unroll
    for (int q = 0; q < 6; ++q) {
      bh[q] = *(const short8*)(bb + q*1024);
      bl[q] = *(const short8*)(bb + q*1024 + 512);
    }
    #pragma unroll
    for (int mi = 0; mi < 2; ++mi) {
      const int mf = wm*2 + mi;
      const int m = mf*16 + (lane & 15);
      const int kg = lane >> 4;
      const int off = m*64 + ((kg ^ ((m>>1)&3)) << 4);
      short8 ah = *(const short8*)((const char*)&sA[buf][0][0] + off);
      short8 al = *(const short8*)((const char*)&sA[buf][1][0] + off);
      #pragma unroll
      for (int q = 0; q < 6; ++q) {
        acc[mi][q] = __builtin_amdgcn_mfma_f32_16x16x32_bf16(ah, bh[q], acc[mi][q], 0, 0, 0);
        acc[mi][q] = __builtin_amdgcn_mfma_f32_16x16x32_bf16(ah, bl[q], acc[mi][q], 0, 0, 0);
        acc[mi][q] = __builtin_amdgcn_mfma_f32_16x16x32_bf16(al, bh[q], acc[mi][q], 0, 0, 0);
      }
    }
  };

  __syncthreads();   // s-tile ready

  // ---- ss chunks (0..257) ----
  write_feats_ss(0, *(const unsigned*)(mss + 2*kp));
  unsigned mvn = *(const unsigned*)(mss + 32 + 2*kp);
  __syncthreads();
  for (int c = 0; c < NCH_SS; ++c) {
    const int buf = c & 1;
    if (c < NCH_SS - 1) {
      unsigned mv = mvn;
      if (c < NCH_SS - 2) mvn = *(const unsigned*)(mss + (c + 2)*32 + 2*kp);
      write_feats_ss(buf ^ 1, mv);
    }
    mfma_step(c, buf);
    __syncthreads();
  }

  // ---- stage v-tile [64][193] over s ----
  for (int i = tid; i < 64*192; i += 256) {
    int r = i / 192, c = i - r*192;
    sSV[r*193 + c] = v1[(size_t)(r0 + r)*192 + c];
  }
  __syncthreads();

  // ---- dd chunks (258..322) ----
  write_feats_dd(0, *(const unsigned*)(mdd + 2*kp));   // chunk 258 -> buf 0
  mvn = *(const unsigned*)(mdd + 32 + 2*kp);
  __syncthreads();
  for (int c = NCH_SS; c < NCH; ++c) {
    const int buf = c & 1;
    if (c < NCH - 1) {
      unsigned mv = mvn;
      if (c < NCH - 2) mvn = *(const unsigned*)(mdd + (c - NCH_SS + 2)*32 + 2*kp);
      write_feats_dd(buf ^ 1, mv);
    }
    mfma_step(c, buf);
    __syncthreads();
  }

  // ---- epilogue: norm + silu / sigmoid ----
  const float nrm = 1.0f / sqrtf((float)P0_2);
  #pragma unroll
  for (int mi = 0; mi < 2; ++mi) {
    const int rowbase = r0 + (wm*2 + mi)*16 + (lane >> 4)*4;
    #pragma unroll
    for (int q = 0; q < 6; ++q) {
      const int col = (wn*6 + q)*16 + (lane & 15);
      #pragma unroll
      for (int r = 0; r < 4; ++r) {
        float val = acc[mi][q][r] * nrm;
        float sg = 1.f / (1.f + __expf(-val));
        if (col < N0H) s2[(size_t)(rowbase + r)*N0H + col] = val * sg;
        else           g2[(size_t)(rowbase + r)*N1H + (col - N0H)] = sg;
      }
    }
  }
}

// ---------------- layer 2 vector path (unchanged this round) ----------------
__global__ __launch_bounds__(256) void k_l2_vector(
    const float* __restrict__ s1, const float* __restrict__ v1,
    const float* __restrict__ w1,
    const float* __restrict__ g2,
    float* __restrict__ v2)
{
  __shared__ float sS[64*129];
  __shared__ float sV[64*193];
  __shared__ float sW[2*8192];

  const int tid = threadIdx.x;
  const int r0 = blockIdx.x * 64;
  const int r = tid >> 2, wq = tid & 3;

  for (int i = tid; i < 64*128; i += 256) {
    int rr = i >> 7, c = i & 127;
    sS[rr*129 + c] = s1[(size_t)(r0 + rr)*128 + c];
  }
  for (int i = tid; i < 64*192; i += 256) {
    int rr = i / 192, c = i - rr*192;
    sV[rr*193 + c] = v1[(size_t)(r0 + rr)*192 + c];
  }
  #pragma unroll
  for (int k = 0; k < 8; ++k) {
    float4 t = *(const float4*)&w1[tid*4 + k*1024];
    *(float4*)&sW[tid*4 + k*1024] = t;
  }
  __syncthreads();

  const float* srow = &sS[r*129];
  const float* vrow = &sV[r*193 + wq*48];
  const float nrm = 1.0f / sqrtf((float)P1_2);

  for (int m = 0; m < 64; ++m) {
    const int cur = m & 1;
    float4 pre[8];
    if (m + 1 < 64) {
      #pragma unroll
      for (int k = 0; k < 8; ++k)
        pre[k] = *(const float4*)&w1[(size_t)(m+1)*8192 + tid*4 + k*1024];
    }
    float T[16];
    #pragma unroll
    for (int k = 0; k < 16; ++k) T[k] = 0.f;
    const float* wb = &sW[cur*8192 + wq*16];
    #pragma unroll 4
    for (int u = 0; u < 128; ++u) {
      float sv = srow[u];
      #pragma unroll
      for (int k = 0; k < 16; k += 4) {
        float4 w4 = *(const float4*)&wb[u*64 + k];
        T[k]   = fmaf(sv, w4.x, T[k]);   T[k+1] = fmaf(sv, w4.y, T[k+1]);
        T[k+2] = fmaf(sv, w4.z, T[k+2]); T[k+3] = fmaf(sv, w4.w, T[k+3]);
      }
    }
    float o0=0.f, o1=0.f, o2=0.f;
    #pragma unroll
    for (int k = 0; k < 16; ++k) {
      float t = T[k];
      o0 = fmaf(t, vrow[k*3+0], o0);
      o1 = fmaf(t, vrow[k*3+1], o1);
      o2 = fmaf(t, vrow[k*3+2], o2);
    }
    o0 += __shfl_down(o0, 2, 4); o0 += __shfl_down(o0, 1, 4);
    o1 += __shfl_down(o1, 2, 4); o1 += __shfl_down(o1, 1, 4);
    o2 += __shfl_down(o2, 2, 4); o2 += __shfl_down(o2, 1, 4);
    if (wq == 0) {
      float g = g2[(size_t)(r0 + r)*64 + m] * nrm;
      float* vo = &v2[(size_t)(r0 + r)*192 + m*3];
      vo[0] = o0*g; vo[1] = o1*g; vo[2] = o2*g;
    }
    if (m + 1 < 64) {
      #pragma unroll
      for (int k = 0; k < 8; ++k)
        *(float4*)&sW[(cur^1)*8192 + tid*4 + k*1024] = pre[k];
    }
    __syncthreads();
  }
}

// ---------------- final (unchanged this round) ----------------
__global__ __launch_bounds__(256) void k_final(
    const float* __restrict__ s2, const float* __restrict__ v2,
    const float* __restrict__ wf,
    const u16* __restrict__ mss, const u16* __restrict__ mdd,
    float* __restrict__ out)
{
  __shared__ float sS[8*129];
  __shared__ float sV[8*193];
  __shared__ u16 sMs[P00_2];
  __shared__ u16 sMd[P11_2];

  const int tid = threadIdx.x;
  const int r0 = blockIdx.x * 8;
  for (int i = tid; i < P00_2; i += 256) sMs[i] = mss[i];
  for (int i = tid; i < P11_2; i += 256) sMd[i] = mdd[i];
  for (int i = tid; i < 8*128; i += 256) { int r = i >> 7, c = i & 127; sS[r*129+c] = s2[(size_t)(r0+r)*128 + c]; }
  for (int i = tid; i < 8*192; i += 256) { int r = i / 192, c = i - r*192; sV[r*193+c] = v2[(size_t)(r0+r)*192 + c]; }
  __syncthreads();

  const int r = tid >> 5, l = tid & 31;
  const float* srow = &sS[r*129];
  const float* vrow = &sV[r*193];
  float acc = 0.f;
  for (int p = l; p < P00_2; p += 32) {
    u16 mv = sMs[p]; int u = mv >> 8, v = mv & 255;
    acc = fmaf(wf[p], srow[u]*srow[v], acc);
  }
  for (int q = l; q < P11_2; q += 32) {
    u16 mv = sMd[q]; int u = mv >> 8, v = mv & 255;
    const float* pa = &vrow[u*3];
    const float* pb = &vrow[v*3];
    float d = (pa[0]*pb[0] + pa[1]*pb[1] + pa[2]*pb[2]) * INV_SQRT3;
    acc = fmaf(wf[P00_2 + q], d, acc);
  }
  #pragma unroll
  for (int off = 16; off >= 1; off >>= 1) acc += __shfl_down(acc, off, 32);
  if (l == 0) out[r0 + r] = acc * (1.0f / sqrtf((float)P0_2));
}

// ---------------- launch ----------------
extern "C" void kernel_launch(void* const* d_in, const int* in_sizes, int n_in,
                              void* d_out, int out_size, void* d_ws, size_t ws_size,
                              hipStream_t stream)
{
  const float* x    = (const float*)d_in[0];
  const float* w0_1 = (const float*)d_in[1];
  const float* w1_1 = (const float*)d_in[2];
  const float* w0_2 = (const float*)d_in[3];
  const float* w1_2 = (const float*)d_in[4];
  const float* w0_f = (const float*)d_in[5];
  float* out = (float*)d_out;
  char* ws = (char*)d_ws;

  if (ws_size < WS_NEED) return;

  u16* mss2 = (u16*)(ws + O_MSS2);
  u16* mdd2 = (u16*)(ws + O_MDD2);
  u16* mss1 = (u16*)(ws + O_MSS1);
  u16* mdd1 = (u16*)(ws + O_MDD1);
  float* w0t1 = (float*)(ws + O_W0T1);
  short* w0f  = (short*)(ws + O_W0F);
  float* s1 = (float*)(ws + O_S1);
  float* v1 = (float*)(ws + O_V1);
  float* s2 = (float*)(ws + O_S2);
  float* g2 = (float*)(ws + O_G2);
  float* v2 = (float*)(ws + O_V2);

  hipLaunchKernelGGL(k_init_maps, dim3(1), dim3(128), 0, stream, mss2, mdd2, mss1, mdd1);
  hipLaunchKernelGGL(k_transpose, dim3((P0_1 + 31)/32, STP/32), dim3(32, 8), 0, stream,
                     w0_1, w0t1, STP, P0_1);
  hipLaunchKernelGGL(k_prep_b, dim3((NCH*12 + 3)/4), dim3(256), 0, stream, w0_2, w0f);
  hipLaunchKernelGGL(k_layer1, dim3(NR/32), dim3(256), 0, stream,
                     x, w0t1, w1_1, mss1, mdd1, s1, v1);
  hipLaunchKernelGGL(k_l2_scalar_mfma, dim3(NR/64), dim3(256), 0, stream,
                     s1, v1, w0f, mss2, mdd2, s2, g2);
  hipLaunchKernelGGL(k_l2_vector, dim3(NR/64), dim3(256), 0, stream,
                     s1, v1, w1_2, g2, v2);
  hipLaunchKernelGGL(k_final, dim3(NR/8), dim3(256), 0, stream,
                     s2, v2, w0_f, mss2, mdd2, out);
}